// Round 1
// baseline (722.409 us; speedup 1.0000x reference)
//
#include <hip/hip_runtime.h>
#include <hip/hip_bf16.h>

// MHA forward: B=4, S=1024, E=1024, H=16, HD=64.
// Outputs concatenated in d_out: out (B,S,E)=4194304 fp32, attn (B,H,S,S)=67108864 fp32.
// Workspace layout (bf16 elems unless noted):
//   Xq/Xk/Xv casts: 3 x 4M, Wq/Wk/Wv/Wo casts: 4 x 1M,
//   Q/K/V (B,H,S,HD): 3 x 4M, O (B*S,E): 4M, stats (m,l) float2 x 64K.
// Total ~64.5 MB.

typedef short bf16x8 __attribute__((ext_vector_type(8)));
typedef float f32x4 __attribute__((ext_vector_type(4)));

__device__ __forceinline__ unsigned short f2bf(float f) {
  union { float f; unsigned u; } v; v.f = f;
  unsigned r = v.u + 0x7FFF + ((v.u >> 16) & 1);   // RNE; inputs are finite
  return (unsigned short)(r >> 16);
}

// ---------------- cast fp32 -> bf16, 8 elems/thread ----------------
__global__ __launch_bounds__(256) void cast_bf16_k(const float* __restrict__ in,
                                                   unsigned short* __restrict__ out, int n) {
  int i = (blockIdx.x * 256 + threadIdx.x) * 8;
  if (i + 8 > n) return;
  float4 a = *(const float4*)(in + i);
  float4 b = *(const float4*)(in + i + 4);
  unsigned short tmp[8] = { f2bf(a.x), f2bf(a.y), f2bf(a.z), f2bf(a.w),
                            f2bf(b.x), f2bf(b.y), f2bf(b.z), f2bf(b.w) };
  *(bf16x8*)(out + i) = *(bf16x8*)tmp;
}

// ---------------- GEMM  C = A(MxK) * W(NxK)^T + bias ----------------
// mode 0: store bf16 permuted to (B,H,S,HD)   (for Q/K/V projections)
// mode 1: store fp32 row-major (M,N)          (final output projection)
__global__ __launch_bounds__(256) void gemm_bt(
    const unsigned short* __restrict__ A,
    const unsigned short* __restrict__ W,
    const float* __restrict__ bias,
    unsigned short* __restrict__ outb,
    float* __restrict__ outf,
    int M, int N, int K, int mode)
{
  __shared__ unsigned short As[128 * 72];   // 64 K-cols + 8 pad (2-way LDS conflict = free)
  __shared__ unsigned short Bs[128 * 72];
  const int tid = threadIdx.x;
  const int wave = tid >> 6, lane = tid & 63, quad = lane >> 4, lc = lane & 15;
  const int wm = (wave >> 1) * 64, wn = (wave & 1) * 64;
  const int m0 = blockIdx.x * 128, n0 = blockIdx.y * 128;
  const int r0 = tid >> 3, g0 = (tid & 7) * 8;

  f32x4 acc[4][4] = {};
  for (int kb = 0; kb < K; kb += 64) {
#pragma unroll
    for (int i = 0; i < 4; i++) {
      int r = r0 + i * 32;
      *(bf16x8*)&As[r * 72 + g0] = *(const bf16x8*)&A[(size_t)(m0 + r) * K + kb + g0];
      *(bf16x8*)&Bs[r * 72 + g0] = *(const bf16x8*)&W[(size_t)(n0 + r) * K + kb + g0];
    }
    __syncthreads();
#pragma unroll
    for (int kk = 0; kk < 2; kk++) {
      bf16x8 af[4], bfr[4];
#pragma unroll
      for (int i = 0; i < 4; i++)
        af[i] = *(const bf16x8*)&As[(wm + i * 16 + lc) * 72 + kk * 32 + quad * 8];
#pragma unroll
      for (int j = 0; j < 4; j++)
        bfr[j] = *(const bf16x8*)&Bs[(wn + j * 16 + lc) * 72 + kk * 32 + quad * 8];
#pragma unroll
      for (int i = 0; i < 4; i++)
#pragma unroll
        for (int j = 0; j < 4; j++)
          acc[i][j] = __builtin_amdgcn_mfma_f32_16x16x32_bf16(af[i], bfr[j], acc[i][j], 0, 0, 0);
    }
    __syncthreads();
  }
  // epilogue: C/D layout col=lane&15, row=quad*4+reg (guide §3, m89-verified)
#pragma unroll
  for (int j = 0; j < 4; j++) {
    int col = n0 + wn + j * 16 + lc;
    float bv = bias[col];
#pragma unroll
    for (int i = 0; i < 4; i++) {
#pragma unroll
      for (int r = 0; r < 4; r++) {
        int row = m0 + wm + i * 16 + quad * 4 + r;
        float v = acc[i][j][r] + bv;
        if (mode == 0) {
          int b = row >> 10, s = row & 1023, h = col >> 6, d = col & 63;
          outb[(((size_t)(b * 16 + h)) * 1024 + s) * 64 + d] = f2bf(v);
        } else {
          outf[(size_t)row * N + col] = v;
        }
      }
    }
  }
}

// ---------------- scores: raw QK^T/8 (causal) + online (m,l) stats ----------------
// grid (B*H=64, S/64=16), block 256 = 4 waves; wave handles 16 q-rows x all 1024 kv.
__global__ __launch_bounds__(256) void attn_scores(
    const unsigned short* __restrict__ Q,   // (B,H,S,HD) bf16
    const unsigned short* __restrict__ Kt,  // (B,H,S,HD) bf16
    float* __restrict__ attn,               // (B*H,S,S) fp32 — raw scores written here
    float2* __restrict__ stats)             // (B*H,S) {m,l}
{
  const int bh = blockIdx.x;
  const int q0 = blockIdx.y * 64;
  const int tid = threadIdx.x;
  const int wave = tid >> 6, lane = tid & 63, quad = lane >> 4, lc = lane & 15;
  const int g0 = q0 + wave * 16;

  const unsigned short* qp = Q + ((size_t)bh * 1024 + g0 + lc) * 64 + quad * 8;
  bf16x8 a0 = *(const bf16x8*)(qp);
  bf16x8 a1 = *(const bf16x8*)(qp + 32);

  float m_[4] = { -INFINITY, -INFINITY, -INFINITY, -INFINITY };
  float l_[4] = { 0.f, 0.f, 0.f, 0.f };
  float* arow = attn + (size_t)bh * 1024 * 1024;

  for (int kt = 0; kt < 64; kt++) {
    int kv0 = kt * 16;
    if (kv0 > g0 + 15) {   // fully masked tile: final attn = 0, write now, PV skips it
#pragma unroll
      for (int r = 0; r < 4; r++)
        arow[(size_t)(g0 + quad * 4 + r) * 1024 + kv0 + lc] = 0.f;
      continue;
    }
    const unsigned short* kp = Kt + ((size_t)bh * 1024 + kv0 + lc) * 64 + quad * 8;
    bf16x8 b0 = *(const bf16x8*)(kp);
    bf16x8 b1 = *(const bf16x8*)(kp + 32);
    f32x4 c = {};
    c = __builtin_amdgcn_mfma_f32_16x16x32_bf16(a0, b0, c, 0, 0, 0);
    c = __builtin_amdgcn_mfma_f32_16x16x32_bf16(a1, b1, c, 0, 0, 0);
#pragma unroll
    for (int r = 0; r < 4; r++) {
      int qr = g0 + quad * 4 + r;
      float s = c[r] * 0.125f;               // / sqrt(HD)
      bool masked = (kv0 + lc) > qr;
      arow[(size_t)qr * 1024 + kv0 + lc] = masked ? 0.f : s;
      float sv = masked ? -INFINITY : s;
      float tm = sv;
#pragma unroll
      for (int off = 1; off < 16; off <<= 1) tm = fmaxf(tm, __shfl_xor(tm, off));
      float te = masked ? 0.f : __expf(s - tm);
#pragma unroll
      for (int off = 1; off < 16; off <<= 1) te += __shfl_xor(te, off);
      if (tm != -INFINITY) {
        float mn = fmaxf(m_[r], tm);
        l_[r] = l_[r] * __expf(m_[r] - mn) + te * __expf(tm - mn);
        m_[r] = mn;
      }
    }
  }
  // lanes 0..3 of each 16-lane group write their quad's 4 rows
  float mm = (lc == 0) ? m_[0] : (lc == 1) ? m_[1] : (lc == 2) ? m_[2] : m_[3];
  float ll = (lc == 0) ? l_[0] : (lc == 1) ? l_[1] : (lc == 2) ? l_[2] : l_[3];
  if (lc < 4) stats[(size_t)bh * 1024 + g0 + quad * 4 + lc] = make_float2(mm, ll);
}

// ---------------- normalize + write attn + P·V ----------------
// grid (B*H=64, S/64=16), block 256. Chunks of 128 kv; P bf16 + V^T bf16 staged in LDS.
__global__ __launch_bounds__(256) void attn_pv(
    float* __restrict__ attn,               // in: raw scores, out: final attn (in place)
    const float2* __restrict__ stats,
    const unsigned short* __restrict__ V,   // (B,H,S,HD) bf16
    unsigned short* __restrict__ O)         // (B*S, E) bf16
{
  __shared__ unsigned short Pl[64 * 136];
  __shared__ unsigned short Vt[64 * 136];
  const int bh = blockIdx.x, b = bh >> 4, h = bh & 15;
  const int q0 = blockIdx.y * 64;
  const int tid = threadIdx.x;
  const int wave = tid >> 6, lane = tid & 63, quad = lane >> 4, lc = lane & 15;
  const int rw = tid >> 2;            // 0..63: this thread's q-row for normalization
  const int cg = (tid & 3) * 32;      // its 32-col group
  const int qrow = q0 + rw;

  float2 st = stats[(size_t)bh * 1024 + qrow];
  const float mrow = st.x;
  const float linv = 1.f / st.y;      // l >= 1 always (diagonal term contributes exp(0))
  float* aprow = attn + ((size_t)bh * 1024 + qrow) * 1024;

  f32x4 acc[4] = {};
  for (int c = 0; c < 8; c++) {
    int kv0 = c * 128;
    if (kv0 > q0 + 63) break;         // block-uniform; remaining attn already 0 from scores pass
    // normalize chunk, write final attn, pack bf16 P into LDS
#pragma unroll
    for (int u = 0; u < 8; u++) {
      int colb = kv0 + cg + u * 4;
      float4 sv = *(const float4*)(aprow + colb);
      float p0 = (colb + 0 <= qrow) ? __expf(sv.x - mrow) * linv : 0.f;
      float p1 = (colb + 1 <= qrow) ? __expf(sv.y - mrow) * linv : 0.f;
      float p2 = (colb + 2 <= qrow) ? __expf(sv.z - mrow) * linv : 0.f;
      float p3 = (colb + 3 <= qrow) ? __expf(sv.w - mrow) * linv : 0.f;
      *(float4*)(aprow + colb) = make_float4(p0, p1, p2, p3);
      unsigned short pk[4] = { f2bf(p0), f2bf(p1), f2bf(p2), f2bf(p3) };
      *(ushort4*)&Pl[rw * 136 + cg + u * 4] = *(ushort4*)pk;
    }
    // stage V^T: Vt[d][kv_local]
#pragma unroll
    for (int i = 0; i < 4; i++) {
      int idx = tid + i * 256;
      int r = idx >> 3, g = (idx & 7) * 8;
      bf16x8 v = *(const bf16x8*)&V[((size_t)bh * 1024 + kv0 + r) * 64 + g];
#pragma unroll
      for (int j = 0; j < 8; j++) Vt[(g + j) * 136 + r] = (unsigned short)v[j];
    }
    __syncthreads();
#pragma unroll
    for (int kk = 0; kk < 4; kk++) {
      bf16x8 a = *(const bf16x8*)&Pl[(wave * 16 + lc) * 136 + kk * 32 + quad * 8];
#pragma unroll
      for (int j = 0; j < 4; j++) {
        bf16x8 bv = *(const bf16x8*)&Vt[(j * 16 + lc) * 136 + kk * 32 + quad * 8];
        acc[j] = __builtin_amdgcn_mfma_f32_16x16x32_bf16(a, bv, acc[j], 0, 0, 0);
      }
    }
    __syncthreads();
  }
  // store O as (B*S, E) bf16, merged heads: col = h*64 + d
#pragma unroll
  for (int j = 0; j < 4; j++) {
    int d = h * 64 + j * 16 + lc;
#pragma unroll
    for (int r = 0; r < 4; r++) {
      int q = q0 + wave * 16 + quad * 4 + r;
      O[((size_t)b * 1024 + q) * 1024 + d] = f2bf(acc[j][r]);
    }
  }
}

extern "C" void kernel_launch(void* const* d_in, const int* in_sizes, int n_in,
                              void* d_out, int out_size, void* d_ws, size_t ws_size,
                              hipStream_t stream) {
  const float* query = (const float*)d_in[0];
  const float* key_t = (const float*)d_in[1];
  const float* value = (const float*)d_in[2];
  // d_in[3] = mask: known causal tril, applied analytically
  const float* Wq = (const float*)d_in[4];
  const float* bq = (const float*)d_in[5];
  const float* Wk = (const float*)d_in[6];
  const float* bk = (const float*)d_in[7];
  const float* Wv = (const float*)d_in[8];
  const float* bv = (const float*)d_in[9];
  const float* Wo = (const float*)d_in[10];
  const float* bo = (const float*)d_in[11];

  unsigned short* Xq  = (unsigned short*)d_ws;
  unsigned short* Xk  = Xq  + 4194304;
  unsigned short* Xv  = Xk  + 4194304;
  unsigned short* Wqb = Xv  + 4194304;
  unsigned short* Wkb = Wqb + 1048576;
  unsigned short* Wvb = Wkb + 1048576;
  unsigned short* Wob = Wvb + 1048576;
  unsigned short* Qb  = Wob + 1048576;
  unsigned short* Kb  = Qb  + 4194304;
  unsigned short* Vb  = Kb  + 4194304;
  unsigned short* Ob  = Vb  + 4194304;
  float2* stats = (float2*)(Ob + 4194304);

  float* outO = (float*)d_out;
  float* attn = outO + 4194304;

  cast_bf16_k<<<2048, 256, 0, stream>>>(query, Xq, 4194304);
  cast_bf16_k<<<2048, 256, 0, stream>>>(key_t, Xk, 4194304);
  cast_bf16_k<<<2048, 256, 0, stream>>>(value, Xv, 4194304);
  cast_bf16_k<<<512, 256, 0, stream>>>(Wq, Wqb, 1048576);
  cast_bf16_k<<<512, 256, 0, stream>>>(Wk, Wkb, 1048576);
  cast_bf16_k<<<512, 256, 0, stream>>>(Wv, Wvb, 1048576);
  cast_bf16_k<<<512, 256, 0, stream>>>(Wo, Wob, 1048576);

  dim3 gproj(32, 8);
  gemm_bt<<<gproj, 256, 0, stream>>>(Xq, Wqb, bq, Qb, nullptr, 4096, 1024, 1024, 0);
  gemm_bt<<<gproj, 256, 0, stream>>>(Xk, Wkb, bk, Kb, nullptr, 4096, 1024, 1024, 0);
  gemm_bt<<<gproj, 256, 0, stream>>>(Xv, Wvb, bv, Vb, nullptr, 4096, 1024, 1024, 0);

  dim3 gattn(64, 16);
  attn_scores<<<gattn, 256, 0, stream>>>(Qb, Kb, attn, stats);
  attn_pv<<<gattn, 256, 0, stream>>>(attn, stats, Vb, Ob);

  gemm_bt<<<gproj, 256, 0, stream>>>(Ob, Wob, bo, nullptr, outO, 4096, 1024, 1024, 1);
}

// Round 2
// 546.889 us; speedup vs baseline: 1.3209x; 1.3209x over previous
//
#include <hip/hip_runtime.h>
#include <hip/hip_bf16.h>

// MHA forward: B=4, S=1024, E=1024, H=16, HD=64.
// d_out: out (B,S,E)=4194304 fp32, then attn (B,H,S,S)=67108864 fp32.
// ws (bf16): Xq/Xk/Xv 3x4M, Wq/Wk/Wv/Wo 4x1M, Qb/Kb (B*S,E) 2x4M,
//            Vt (B*H,HD,S) 4M, Ob (B*S,E) 4M  => 32M elems = 64 MB.

typedef short bf16x8 __attribute__((ext_vector_type(8)));
typedef float f32x4 __attribute__((ext_vector_type(4)));

__device__ __forceinline__ unsigned short f2bf(float f) {
  union { float f; unsigned u; } v; v.f = f;
  unsigned r = v.u + 0x7FFF + ((v.u >> 16) & 1);   // RNE; finite inputs
  return (unsigned short)(r >> 16);
}

// async global->LDS, 16B per lane; LDS dest = wave-uniform base + lane*16 (m97/m104)
__device__ __forceinline__ void gload16(const unsigned short* g, unsigned short* l) {
  __builtin_amdgcn_global_load_lds(
      (const __attribute__((address_space(1))) unsigned int*)g,
      (__attribute__((address_space(3))) unsigned int*)l, 16, 0, 0);
}

// ---------------- casts (fp32 -> bf16), 8 elems/thread ----------------
__global__ __launch_bounds__(256) void cast3_k(
    const float* __restrict__ a, const float* __restrict__ b,
    const float* __restrict__ c,
    unsigned short* __restrict__ oa, unsigned short* __restrict__ ob,
    unsigned short* __restrict__ oc) {
  const float* in = blockIdx.y == 0 ? a : blockIdx.y == 1 ? b : c;
  unsigned short* out = blockIdx.y == 0 ? oa : blockIdx.y == 1 ? ob : oc;
  int i = (blockIdx.x * 256 + threadIdx.x) * 8;
  float4 x = *(const float4*)(in + i);
  float4 y = *(const float4*)(in + i + 4);
  unsigned short t[8] = { f2bf(x.x), f2bf(x.y), f2bf(x.z), f2bf(x.w),
                          f2bf(y.x), f2bf(y.y), f2bf(y.z), f2bf(y.w) };
  *(bf16x8*)(out + i) = *(bf16x8*)t;
}

__global__ __launch_bounds__(256) void cast4_k(
    const float* __restrict__ a, const float* __restrict__ b,
    const float* __restrict__ c, const float* __restrict__ d,
    unsigned short* __restrict__ oa, unsigned short* __restrict__ ob,
    unsigned short* __restrict__ oc, unsigned short* __restrict__ od) {
  const float* in = blockIdx.y == 0 ? a : blockIdx.y == 1 ? b : blockIdx.y == 2 ? c : d;
  unsigned short* out = blockIdx.y == 0 ? oa : blockIdx.y == 1 ? ob : blockIdx.y == 2 ? oc : od;
  int i = (blockIdx.x * 256 + threadIdx.x) * 8;
  float4 x = *(const float4*)(in + i);
  float4 y = *(const float4*)(in + i + 4);
  unsigned short t[8] = { f2bf(x.x), f2bf(x.y), f2bf(x.z), f2bf(x.w),
                          f2bf(y.x), f2bf(y.y), f2bf(y.z), f2bf(y.w) };
  *(bf16x8*)(out + i) = *(bf16x8*)t;
}

// ---------------- GEMM core: 128x128 tile, BK=64, global_load_lds + XOR swizzle ----
// LDS granule g of row r holds global granule g^(r&7): staging is unpadded
// (global_load_lds requires it) and fragment ds_read_b128 stays 2-way max (free).
__device__ __forceinline__ void gemm_core(
    const unsigned short* __restrict__ A, const unsigned short* __restrict__ W,
    int m0, int n0, int K, unsigned short* As, unsigned short* Bs, f32x4 acc[4][4])
{
  const int tid = threadIdx.x;
  const int w = tid >> 6, lane = tid & 63, quad = lane >> 4, lc = lane & 15;
  const int wm = (w >> 1) * 64, wn = (w & 1) * 64;
  const int lrow = lane >> 3, lg = lane & 7;

  for (int kb = 0; kb < K; kb += 64) {
#pragma unroll
    for (int t = 0; t < 4; t++) {
      int row = w * 32 + t * 8 + lrow;
      int gsw = lg ^ (row & 7);
      gload16(&A[(size_t)(m0 + row) * K + kb + gsw * 8], &As[(w * 32 + t * 8) * 64]);
      gload16(&W[(size_t)(n0 + row) * K + kb + gsw * 8], &Bs[(w * 32 + t * 8) * 64]);
    }
    __syncthreads();
#pragma unroll
    for (int kk = 0; kk < 2; kk++) {
      bf16x8 af[4], bfr[4];
#pragma unroll
      for (int i = 0; i < 4; i++) {
        int ra = wm + i * 16 + lc;
        af[i] = *(const bf16x8*)&As[ra * 64 + (((kk * 4 + quad) ^ (ra & 7)) * 8)];
      }
#pragma unroll
      for (int j = 0; j < 4; j++) {
        int rb = wn + j * 16 + lc;
        bfr[j] = *(const bf16x8*)&Bs[rb * 64 + (((kk * 4 + quad) ^ (rb & 7)) * 8)];
      }
#pragma unroll
      for (int i = 0; i < 4; i++)
#pragma unroll
        for (int j = 0; j < 4; j++)
          acc[i][j] = __builtin_amdgcn_mfma_f32_16x16x32_bf16(af[i], bfr[j], acc[i][j], 0, 0, 0);
    }
    __syncthreads();
  }
}

// QKV projections in one launch (grid.z = 0,1,2). Q/K: bf16 (B*S,E) row-major.
// V: bf16 head-transposed (B*H, HD, S) so PV B-fragments are direct global loads.
__global__ __launch_bounds__(256) void gemm_qkv(
    const unsigned short* __restrict__ Xq, const unsigned short* __restrict__ Xk,
    const unsigned short* __restrict__ Xv,
    const unsigned short* __restrict__ Wq, const unsigned short* __restrict__ Wk,
    const unsigned short* __restrict__ Wv,
    const float* __restrict__ bq, const float* __restrict__ bk, const float* __restrict__ bv,
    unsigned short* __restrict__ Qb, unsigned short* __restrict__ Kb,
    unsigned short* __restrict__ Vt)
{
  __shared__ __align__(16) unsigned short As[128 * 64];
  __shared__ __align__(16) unsigned short Bs[128 * 64];
  const int z = blockIdx.z;
  const unsigned short* A = z == 0 ? Xq : z == 1 ? Xk : Xv;
  const unsigned short* W = z == 0 ? Wq : z == 1 ? Wk : Wv;
  const float* bias = z == 0 ? bq : z == 1 ? bk : bv;
  unsigned short* outRM = z == 0 ? Qb : Kb;
  const int m0 = blockIdx.x * 128, n0 = blockIdx.y * 128;
  const int tid = threadIdx.x;
  const int w = tid >> 6, lane = tid & 63, quad = lane >> 4, lc = lane & 15;
  const int wm = (w >> 1) * 64, wn = (w & 1) * 64;

  f32x4 acc[4][4] = {};
  gemm_core(A, W, m0, n0, 1024, As, Bs, acc);

#pragma unroll
  for (int j = 0; j < 4; j++) {
    int col = n0 + wn + j * 16 + lc;
    float bvl = bias[col];
#pragma unroll
    for (int i = 0; i < 4; i++)
#pragma unroll
      for (int r = 0; r < 4; r++) {
        int row = m0 + wm + i * 16 + quad * 4 + r;
        float v = acc[i][j][r] + bvl;
        if (z < 2)
          outRM[(size_t)row * 1024 + col] = f2bf(v);
        else
          Vt[(((size_t)((row >> 10) * 16 + (col >> 6))) * 64 + (col & 63)) * 1024 + (row & 1023)] = f2bf(v);
      }
  }
}

// Final projection: O(bf16) @ Wo^T + bo -> fp32 out.
__global__ __launch_bounds__(256) void gemm_out(
    const unsigned short* __restrict__ A, const unsigned short* __restrict__ W,
    const float* __restrict__ bias, float* __restrict__ outf)
{
  __shared__ __align__(16) unsigned short As[128 * 64];
  __shared__ __align__(16) unsigned short Bs[128 * 64];
  const int m0 = blockIdx.x * 128, n0 = blockIdx.y * 128;
  const int tid = threadIdx.x;
  const int w = tid >> 6, lane = tid & 63, quad = lane >> 4, lc = lane & 15;
  const int wm = (w >> 1) * 64, wn = (w & 1) * 64;

  f32x4 acc[4][4] = {};
  gemm_core(A, W, m0, n0, 1024, As, Bs, acc);

#pragma unroll
  for (int j = 0; j < 4; j++) {
    int col = n0 + wn + j * 16 + lc;
    float bvl = bias[col];
#pragma unroll
    for (int i = 0; i < 4; i++)
#pragma unroll
      for (int r = 0; r < 4; r++) {
        int row = m0 + wm + i * 16 + quad * 4 + r;
        outf[(size_t)row * 1024 + col] = acc[i][j][r] + bvl;
      }
  }
}

// ---------------- fused attention: two-pass flash, no block barriers ----------------
// grid (B*H=64, S/64=16), 4 waves; wave owns 16 q-rows, fully independent.
// Pass A: per-lane online (m,l) over kv tiles (no shuffles in loop).
// Pass B: recompute QK^T, write normalized attn fp32 once, P(bf16)->wave-private LDS,
//         PV MFMA with B-frags loaded directly from head-transposed V.
__global__ __launch_bounds__(256) void attn_fused(
    const unsigned short* __restrict__ Qb,   // (B*S,E) bf16
    const unsigned short* __restrict__ Kb,   // (B*S,E) bf16
    const unsigned short* __restrict__ Vt,   // (B*H,HD,S) bf16
    float* __restrict__ attn,                // (B*H,S,S) fp32
    unsigned short* __restrict__ O)          // (B*S,E) bf16
{
  __shared__ __align__(16) unsigned short Pl[4][16][40];  // per-wave P tile, pad 40 (80B stride: conflict-free)
  const int bh = blockIdx.x, b = bh >> 4, h = bh & 15;
  const int q0 = blockIdx.y * 64;
  const int tid = threadIdx.x;
  const int w = tid >> 6, lane = tid & 63, quad = lane >> 4, lc = lane & 15;
  const int g0 = q0 + w * 16;
  const int kt_d = g0 >> 4;                  // diagonal tile index (same for all 16 rows of wave)

  const unsigned short* qp = Qb + ((size_t)(b * 1024 + g0 + lc)) * 1024 + h * 64 + quad * 8;
  bf16x8 a0 = *(const bf16x8*)qp;
  bf16x8 a1 = *(const bf16x8*)(qp + 32);

  float m_[4] = { -1e30f, -1e30f, -1e30f, -1e30f };
  float l_[4] = { 0.f, 0.f, 0.f, 0.f };

  // ---- pass A: online stats, per-lane ----
  for (int kt = 0; kt <= kt_d; kt++) {
    int kv0 = kt * 16;
    const unsigned short* kp = Kb + ((size_t)(b * 1024 + kv0 + lc)) * 1024 + h * 64 + quad * 8;
    bf16x8 b0 = *(const bf16x8*)kp;
    bf16x8 b1 = *(const bf16x8*)(kp + 32);
    f32x4 c = {};
    c = __builtin_amdgcn_mfma_f32_16x16x32_bf16(a0, b0, c, 0, 0, 0);
    c = __builtin_amdgcn_mfma_f32_16x16x32_bf16(a1, b1, c, 0, 0, 0);
#pragma unroll
    for (int r = 0; r < 4; r++) {
      int qr = g0 + quad * 4 + r;
      float s = c[r] * 0.125f;
      float sv = (kv0 + lc) > qr ? -1e30f : s;   // finite sentinel: exp underflows, no NaN
      float mn = fmaxf(m_[r], sv);
      l_[r] = l_[r] * __expf(m_[r] - mn) + __expf(sv - mn);
      m_[r] = mn;
    }
  }
  // one cross-lane reduction per row group (16 lanes share a row)
  float mofs[4];
#pragma unroll
  for (int r = 0; r < 4; r++) {
    float mT = m_[r];
#pragma unroll
    for (int off = 1; off < 16; off <<= 1) mT = fmaxf(mT, __shfl_xor(mT, off));
    float lt = l_[r] * __expf(m_[r] - mT);
#pragma unroll
    for (int off = 1; off < 16; off <<= 1) lt += __shfl_xor(lt, off);
    mofs[r] = mT + __logf(lt);                   // p = exp(s - m - ln l)
  }

  // ---- pass B: recompute, normalize, write attn, PV ----
  float* arow = attn + (size_t)bh * 1024 * 1024;
  f32x4 oacc[4] = {};
  for (int kt2 = 0; kt2 <= kt_d; kt2 += 2) {
#pragma unroll
    for (int tt = 0; tt < 2; tt++) {
      int kt = kt2 + tt;
      int kv0 = kt * 16;
      if (kt <= kt_d) {                          // wave-uniform branch
        const unsigned short* kp = Kb + ((size_t)(b * 1024 + kv0 + lc)) * 1024 + h * 64 + quad * 8;
        bf16x8 b0 = *(const bf16x8*)kp;
        bf16x8 b1 = *(const bf16x8*)(kp + 32);
        f32x4 c = {};
        c = __builtin_amdgcn_mfma_f32_16x16x32_bf16(a0, b0, c, 0, 0, 0);
        c = __builtin_amdgcn_mfma_f32_16x16x32_bf16(a1, b1, c, 0, 0, 0);
#pragma unroll
        for (int r = 0; r < 4; r++) {
          int qr = g0 + quad * 4 + r;
          float p = (kv0 + lc) > qr ? 0.f : __expf(c[r] * 0.125f - mofs[r]);
          arow[(size_t)qr * 1024 + kv0 + lc] = p;
          Pl[w][quad * 4 + r][tt * 16 + lc] = f2bf(p);
        }
      } else {
#pragma unroll
        for (int r = 0; r < 4; r++) Pl[w][quad * 4 + r][tt * 16 + lc] = 0;
      }
    }
    // PV over this 32-kv chunk; wave-private LDS, compiler inserts lgkmcnt waits
    bf16x8 pa = *(const bf16x8*)&Pl[w][lc][quad * 8];
#pragma unroll
    for (int j = 0; j < 4; j++) {
      const unsigned short* vp = Vt + ((size_t)bh * 64 + j * 16 + lc) * 1024 + kt2 * 16 + quad * 8;
      bf16x8 bv = *(const bf16x8*)vp;
      oacc[j] = __builtin_amdgcn_mfma_f32_16x16x32_bf16(pa, bv, oacc[j], 0, 0, 0);
    }
  }

  // ---- zero-fill fully-masked region [g0+16, 1024) for the wave's 16 rows ----
  {
    int rr = lane >> 2, cl = lane & 3;
    float4 z = make_float4(0.f, 0.f, 0.f, 0.f);
    for (int c0 = g0 + 16 + cl * 4; c0 < 1024; c0 += 16)
      *(float4*)&arow[(size_t)(g0 + rr) * 1024 + c0] = z;
  }

  // ---- store O (B*S,E) bf16, heads merged ----
#pragma unroll
  for (int j = 0; j < 4; j++) {
    int d = h * 64 + j * 16 + lc;
#pragma unroll
    for (int r = 0; r < 4; r++) {
      int q = g0 + quad * 4 + r;
      O[((size_t)(b * 1024 + q)) * 1024 + d] = f2bf(oacc[j][r]);
    }
  }
}

extern "C" void kernel_launch(void* const* d_in, const int* in_sizes, int n_in,
                              void* d_out, int out_size, void* d_ws, size_t ws_size,
                              hipStream_t stream) {
  const float* query = (const float*)d_in[0];
  const float* key_t = (const float*)d_in[1];
  const float* value = (const float*)d_in[2];
  // d_in[3] = mask: causal tril, applied analytically
  const float* Wq = (const float*)d_in[4];
  const float* bq = (const float*)d_in[5];
  const float* Wk = (const float*)d_in[6];
  const float* bk = (const float*)d_in[7];
  const float* Wv = (const float*)d_in[8];
  const float* bv = (const float*)d_in[9];
  const float* Wo = (const float*)d_in[10];
  const float* bo = (const float*)d_in[11];

  unsigned short* Xq  = (unsigned short*)d_ws;
  unsigned short* Xk  = Xq  + 4194304;
  unsigned short* Xv  = Xk  + 4194304;
  unsigned short* Wqb = Xv  + 4194304;
  unsigned short* Wkb = Wqb + 1048576;
  unsigned short* Wvb = Wkb + 1048576;
  unsigned short* Wob = Wvb + 1048576;
  unsigned short* Qb  = Wob + 1048576;
  unsigned short* Kb  = Qb  + 4194304;
  unsigned short* Vtb = Kb  + 4194304;
  unsigned short* Ob  = Vtb + 4194304;

  float* outO = (float*)d_out;
  float* attn = outO + 4194304;

  cast3_k<<<dim3(2048, 3), 256, 0, stream>>>(query, key_t, value, Xq, Xk, Xv);
  cast4_k<<<dim3(512, 4), 256, 0, stream>>>(Wq, Wk, Wv, Wo, Wqb, Wkb, Wvb, Wob);

  gemm_qkv<<<dim3(32, 8, 3), 256, 0, stream>>>(Xq, Xk, Xv, Wqb, Wkb, Wvb,
                                               bq, bk, bv, Qb, Kb, Vtb);

  attn_fused<<<dim3(64, 16), 256, 0, stream>>>(Qb, Kb, Vtb, attn, Ob);

  gemm_out<<<dim3(32, 8), 256, 0, stream>>>(Ob, Wob, bo, outO);
}